// Round 8
// baseline (235.307 us; speedup 1.0000x reference)
//
#include <hip/hip_runtime.h>
#include <hip/hip_bf16.h>

#define B_  32
#define T_  2048
#define DH_ 1024
#define DS_ 1024
#define A_  512
#define M_  (B_ * T_)   // 65536

typedef __attribute__((ext_vector_type(8))) short bf16x8;
typedef __attribute__((ext_vector_type(4))) float f32x4;

__device__ __forceinline__ unsigned short f2bf(float f) {
    union { float f; unsigned u; } v; v.f = f;
    unsigned r = 0x7FFFu + ((v.u >> 16) & 1u);
    return (unsigned short)((v.u + r) >> 16);
}
__device__ __forceinline__ float bflo(unsigned u) {
    union { unsigned u; float f; } v; v.u = u << 16; return v.f;
}
__device__ __forceinline__ float bfhi(unsigned u) {
    union { unsigned u; float f; } v; v.u = u & 0xFFFF0000u; return v.f;
}
__device__ __forceinline__ float fast_tanh(float x) {
    float cx = fminf(fmaxf(x, -9.f), 9.f);
    float e2 = __expf(2.f * cx);
    return (e2 - 1.f) / (e2 + 1.f);
}
// pack two f32 -> two bf16 (round-half-up)
__device__ __forceinline__ unsigned pack_bf2(float lo, float hi) {
    union { float f; unsigned u; } a, b;
    a.f = lo; b.f = hi;
    return __builtin_amdgcn_perm(b.u + 0x8000u, a.u + 0x8000u, 0x07060302u);
}

// ---- zero e [M_] ---------------------------------------------------------
__global__ void zero_e(float* __restrict__ e) {
    e[blockIdx.x * 256 + threadIdx.x] = 0.f;
}

// ---- U_t[a][k] = bf16(U_a[k][a]) -----------------------------------------
__global__ void prep_ut(const float* __restrict__ U, unsigned short* __restrict__ Ut) {
    int o = blockIdx.x * 256 + threadIdx.x;
    int a = o >> 10, k = o & (DH_ - 1);
    Ut[o] = f2bf(U[k * A_ + a]);
}

// ---- hb = bf16(h), 8 elems/thread ----------------------------------------
__global__ void conv_h(const float* __restrict__ h, unsigned int* __restrict__ hb) {
    size_t i = ((size_t)blockIdx.x * 256 + threadIdx.x) * 8;
    float4 a = *(const float4*)(h + i);
    float4 b = *(const float4*)(h + i + 4);
    uint4 o;
    o.x = pack_bf2(a.x, a.y);
    o.y = pack_bf2(a.z, a.w);
    o.z = pack_bf2(b.x, b.y);
    o.w = pack_bf2(b.z, b.w);
    *(uint4*)(hb + i / 2) = o;
}

// ---- Ws[b][a] = s[b,:] . W_a[:,a]  (k-split 4-way + LDS reduce) ----------
__global__ void ws_gemv2(const float* __restrict__ s, const float* __restrict__ W,
                         float* __restrict__ Ws) {
    __shared__ float red[4][64];
    const int blk = blockIdx.x;
    const int b = blk >> 3, a0 = (blk & 7) * 64;
    const int tid = threadIdx.x;
    const int a = a0 + (tid & 63), kq = tid >> 6;
    const float* sp = s + b * DS_ + kq * 256;
    const float* wp = W + (size_t)(kq * 256) * A_ + a;
    float acc = 0.f;
#pragma unroll 8
    for (int k = 0; k < 256; ++k) acc += sp[k] * wp[(size_t)k * A_];
    red[kq][tid & 63] = acc;
    __syncthreads();
    if (tid < 64)
        Ws[b * A_ + a0 + tid] = red[0][tid] + red[1][tid] + red[2][tid] + red[3][tid];
}

// ---- main GEMM: BM=256, BN=128, BK=64, 8 waves (4Mx2N), 3-deep LDS
// pipeline with counted vmcnt(6) (never 0 in-loop), raw s_barrier (one per
// K-step), both operands via global_load_lds w=16, granule XOR swizzle
// (g ^= row&7, pre-swizzled source + swizzled read -> 0 bank conflicts),
// setprio around the 32-MFMA cluster. XCD-chunked bid swizzle.
__global__ void __launch_bounds__(512, 1)
gemm_pipe(const unsigned short* __restrict__ hb,
          const unsigned short* __restrict__ Ut,
          const float* __restrict__ Ws, const float* __restrict__ va,
          float* __restrict__ e) {
    __shared__ unsigned short As[3][256][64];   // 96 KB
    __shared__ unsigned short Bs[3][128][64];   // 48 KB

    const int tid = threadIdx.x;
    // XCD-chunk swizzle: nwg = 1024 (256 tm x 4 tn), 128 wg/XCD
    const int bid0 = blockIdx.x;
    const int bid = (bid0 & 7) * 128 + (bid0 >> 3);
    const int tn = bid & 3, tm = bid >> 2;      // tn fast: A-panel same XCD
    const int rowBase = tm * 256, nBase = tn * 128;

    const int lane = tid & 63;
    const int wid = tid >> 6;                   // 8 waves: 4(M) x 2(N)
    const int wm = wid >> 1, wn = wid & 1;      // wave tile 64(m) x 64(n)
    const int lr = lane & 15, kg = lane >> 4;
    const int x7 = lane & 7;                    // row&7 for frag reads

    f32x4 acc[4][4];
#pragma unroll
    for (int i = 0; i < 4; ++i)
#pragma unroll
        for (int j = 0; j < 4; ++j) acc[i][j] = (f32x4){0.f, 0.f, 0.f, 0.f};

    // stage one K-tile (A: 4 gls, B: 2 gls per thread = 6 loads -> vmcnt unit)
    auto stageA = [&](int buf, int tile) {
        const int k0 = tile * 64;
#pragma unroll
        for (int j = 0; j < 4; ++j) {
            int byt = j * 8192 + tid * 16;      // byte off in 32 KB A tile
            int r = byt >> 7;                   // row 0..255
            int g = ((byt >> 4) & 7) ^ (r & 7); // swizzled source granule
            const unsigned short* ga = hb + (size_t)(rowBase + r) * DH_ + k0 + g * 8;
            __builtin_amdgcn_global_load_lds(
                (const __attribute__((address_space(1))) unsigned int*)ga,
                (__attribute__((address_space(3))) unsigned int*)(&As[buf][0][0] + (byt >> 1)),
                16, 0, 0);
        }
    };
    auto stageB = [&](int buf, int tile) {
        const int k0 = tile * 64;
#pragma unroll
        for (int j = 0; j < 2; ++j) {
            int byt = j * 8192 + tid * 16;      // byte off in 16 KB B tile
            int r = byt >> 7;                   // row 0..127
            int g = ((byt >> 4) & 7) ^ (r & 7);
            const unsigned short* gb = Ut + (size_t)(nBase + r) * DH_ + k0 + g * 8;
            __builtin_amdgcn_global_load_lds(
                (const __attribute__((address_space(1))) unsigned int*)gb,
                (__attribute__((address_space(3))) unsigned int*)(&Bs[buf][0][0] + (byt >> 1)),
                16, 0, 0);
        }
    };

    // prologue: tiles 0 and 1 in flight
    stageA(0, 0); stageB(0, 0);
    stageA(1, 1); stageB(1, 1);

#pragma unroll 1
    for (int t = 0; t < DH_ / 64; ++t) {
        // tile t landed (its 6 loads are oldest); t+1, t+2 may fly
        asm volatile("s_waitcnt vmcnt(6)" ::: "memory");
        __builtin_amdgcn_s_barrier();
        __builtin_amdgcn_sched_barrier(0);

        const int buf = t % 3;
        const unsigned short* Ab = &As[buf][0][0];
        const unsigned short* Bb = &Bs[buf][0][0];

        bf16x8 af[2][4], bq[2][4];
#pragma unroll
        for (int kh = 0; kh < 2; ++kh) {
            const int gsw = ((kh * 4 + kg) ^ x7) * 8;
#pragma unroll
            for (int nf = 0; nf < 4; ++nf) {
                int rb = wn * 64 + nf * 16 + lr;
                bq[kh][nf] = *(const bf16x8*)(Bb + rb * 64 + gsw);
            }
#pragma unroll
            for (int mf = 0; mf < 4; ++mf) {
                int ra = wm * 64 + mf * 16 + lr;
                af[kh][mf] = *(const bf16x8*)(Ab + ra * 64 + gsw);
            }
        }

        // stage tile t+2 (uniform: wraps at the tail to keep vmcnt exact)
        const int tt = (t + 2) & 15;
        const int buf2 = (t + 2) % 3;
        stageA(buf2, tt);
        stageB(buf2, tt);

        __builtin_amdgcn_s_setprio(1);
#pragma unroll
        for (int kh = 0; kh < 2; ++kh)
#pragma unroll
            for (int mf = 0; mf < 4; ++mf)
#pragma unroll
                for (int nf = 0; nf < 4; ++nf)
                    acc[mf][nf] = __builtin_amdgcn_mfma_f32_16x16x32_bf16(
                        af[kh][mf], bq[kh][nf], acc[mf][nf], 0, 0, 0);
        __builtin_amdgcn_s_setprio(0);
    }
    asm volatile("s_waitcnt vmcnt(0)" ::: "memory");

    // epilogue: e[row] += sum_a tanh(acc + Ws[b][a]) * v[a]
    const int bIdx = rowBase >> 11;
    const float* WsRow = Ws + bIdx * A_;
    float wsv[4], vav[4];
#pragma unroll
    for (int nf = 0; nf < 4; ++nf) {
        int a = nBase + wn * 64 + nf * 16 + lr;
        wsv[nf] = WsRow[a];
        vav[nf] = va[a];
    }
#pragma unroll
    for (int mf = 0; mf < 4; ++mf) {
#pragma unroll
        for (int j = 0; j < 4; ++j) {
            float ssum = 0.f;
#pragma unroll
            for (int nf = 0; nf < 4; ++nf) {
                float x = acc[mf][nf][j] + wsv[nf];
                ssum += fast_tanh(x) * vav[nf];
            }
            ssum += __shfl_xor(ssum, 1);
            ssum += __shfl_xor(ssum, 2);
            ssum += __shfl_xor(ssum, 4);
            ssum += __shfl_xor(ssum, 8);
            if (lr == 0) {
                int row = rowBase + wm * 64 + mf * 16 + kg * 4 + j;
                atomicAdd(&e[row], ssum);
            }
        }
    }
}

// ---- fused softmax + context (bf16 h): block = (b, dseg of 128 d) --------
__global__ void smax_ctx(const float* __restrict__ e, const unsigned int* __restrict__ hb,
                         float* __restrict__ c) {
    __shared__ float al[T_];
    __shared__ float red[8];
    __shared__ float2 part[256];
    const int b = blockIdx.x >> 3, dseg = blockIdx.x & 7;
    const int tid = threadIdx.x;
    const float* ep = e + (size_t)b * T_;

    float4 v0 = ((const float4*)ep)[tid * 2];
    float4 v1 = ((const float4*)ep)[tid * 2 + 1];
    float m = fmaxf(fmaxf(fmaxf(v0.x, v0.y), fmaxf(v0.z, v0.w)),
                    fmaxf(fmaxf(v1.x, v1.y), fmaxf(v1.z, v1.w)));
#pragma unroll
    for (int off = 1; off < 64; off <<= 1) m = fmaxf(m, __shfl_xor(m, off));
    const int wv = tid >> 6;
    if ((tid & 63) == 0) red[wv] = m;
    __syncthreads();
    m = fmaxf(fmaxf(red[0], red[1]), fmaxf(red[2], red[3]));
    float e0 = __expf(v0.x - m), e1 = __expf(v0.y - m);
    float e2 = __expf(v0.z - m), e3 = __expf(v0.w - m);
    float e4 = __expf(v1.x - m), e5 = __expf(v1.y - m);
    float e6 = __expf(v1.z - m), e7 = __expf(v1.w - m);
    float ssum = e0 + e1 + e2 + e3 + e4 + e5 + e6 + e7;
#pragma unroll
    for (int off = 1; off < 64; off <<= 1) ssum += __shfl_xor(ssum, off);
    if ((tid & 63) == 0) red[4 + wv] = ssum;
    al[tid * 8 + 0] = e0; al[tid * 8 + 1] = e1;
    al[tid * 8 + 2] = e2; al[tid * 8 + 3] = e3;
    al[tid * 8 + 4] = e4; al[tid * 8 + 5] = e5;
    al[tid * 8 + 6] = e6; al[tid * 8 + 7] = e7;
    __syncthreads();
    const float inv = 1.f / (red[4] + red[5] + red[6] + red[7]);

    // context: 2 adjacent d per thread (one uint), 4 t-streams
    const int cu = dseg * 64 + (tid & 63);      // uint column
    const int ts = tid >> 6;                    // 0..3
    const unsigned int* hp = hb + ((size_t)b * T_ + ts) * (DH_ / 2) + cu;
    float a0 = 0.f, a1 = 0.f;
#pragma unroll 8
    for (int i = 0; i < T_ / 4; ++i) {
        float w = al[4 * i + ts];
        unsigned int v = hp[(size_t)(4 * i) * (DH_ / 2)];
        a0 += w * bflo(v);
        a1 += w * bfhi(v);
    }
    part[tid] = make_float2(a0, a1);
    __syncthreads();
    if (tid < 64) {
        float2 p0 = part[tid], p1 = part[tid + 64], p2 = part[tid + 128], p3 = part[tid + 192];
        float r0 = (p0.x + p1.x + p2.x + p3.x) * inv;
        float r1 = (p0.y + p1.y + p2.y + p3.y) * inv;
        float* cp = c + (size_t)b * DH_ + dseg * 128 + tid * 2;
        cp[0] = r0; cp[1] = r1;
    }
}

extern "C" void kernel_launch(void* const* d_in, const int* in_sizes, int n_in,
                              void* d_out, int out_size, void* d_ws, size_t ws_size,
                              hipStream_t stream) {
    const float* s   = (const float*)d_in[0];
    const float* h   = (const float*)d_in[1];
    const float* W_a = (const float*)d_in[2];
    const float* U_a = (const float*)d_in[3];
    const float* v_a = (const float*)d_in[4];
    float* c = (float*)d_out;

    // workspace: e | Ws | Ut | hb  (~129.3 MB)
    const size_t off_Ws = (size_t)M_ * 4;
    const size_t off_Ut = off_Ws + (size_t)B_ * A_ * 4;
    const size_t off_hb = off_Ut + (size_t)A_ * DH_ * 2;

    float* e  = (float*)d_ws;
    float* Ws = (float*)((char*)d_ws + off_Ws);
    unsigned short* Ut = (unsigned short*)((char*)d_ws + off_Ut);
    unsigned short* hb = (unsigned short*)((char*)d_ws + off_hb);

    zero_e<<<M_ / 256, 256, 0, stream>>>(e);
    prep_ut<<<(A_ * DH_) / 256, 256, 0, stream>>>(U_a, Ut);
    ws_gemv2<<<B_ * 8, 256, 0, stream>>>(s, W_a, Ws);
    conv_h<<<(M_ * (size_t)DH_) / (256 * 8), 256, 0, stream>>>(h, (unsigned int*)hb);
    gemm_pipe<<<(M_ / 256) * (A_ / 128), 512, 0, stream>>>(hb, Ut, Ws, v_a, e);
    smax_ctx<<<B_ * 8, 256, 0, stream>>>(e, (const unsigned int*)hb, c);
}